// Round 11
// baseline (279.953 us; speedup 1.0000x reference)
//
#include <hip/hip_runtime.h>

typedef __attribute__((ext_vector_type(8))) short short8;   // 8 bf16 (4 VGPRs)
typedef __attribute__((ext_vector_type(4))) float f32x4;
typedef __attribute__((ext_vector_type(8))) unsigned short ushort8;

__device__ __forceinline__ unsigned short f2bf(float f) {
  unsigned int u = __builtin_bit_cast(unsigned int, f);
  u += 0x7fffu + ((u >> 16) & 1u);   // RNE
  return (unsigned short)(u >> 16);
}
__device__ __forceinline__ float bf2f(unsigned short b) {
  return __builtin_bit_cast(float, ((unsigned int)b) << 16);
}
__device__ __forceinline__ void gload_lds16(const void* g, void* l) {
  __builtin_amdgcn_global_load_lds(
      (const __attribute__((address_space(1))) void*)g,
      (__attribute__((address_space(3))) void*)l, 16, 0, 0);
}

// ---------------- W1/W2 -> transposed bf16 (one kernel) --------------------------
__global__ __launch_bounds__(256) void cvt_weights(
    const float* __restrict__ W1, const float* __restrict__ W2,
    unsigned short* __restrict__ w1t, unsigned short* __restrict__ w2t)
{
  int idx = blockIdx.x * 256 + threadIdx.x;
  if (idx < 131072) {                    // W1 [512][256] -> w1t [256][512]
    int n = idx >> 9, k = idx & 511;
    w1t[idx] = f2bf(W1[(size_t)k * 256 + n]);
  } else if (idx < 131072 + 16384) {     // W2 [256][64] -> w2t [64][256]
    int i = idx - 131072;
    int n = i >> 8, k = i & 255;
    w2t[i] = f2bf(W2[(size_t)k * 64 + n]);
  }
}

// ---------------- GEMM1: H1_bf16[M,256] = x_f32[M,512] @ W1 (cast fused) ---------
// 64x256 tile, BK=32, dbuf + COUNTED vmcnt(6) + raw s_barrier (T4): prefetch for
// tile k+1 stays in flight across the barrier; no per-step vmcnt(0) drain.
__global__ __launch_bounds__(256) void gemm1_mfma(
    const float* __restrict__ x,             // [M][512] fp32
    const unsigned short* __restrict__ w1t,  // [256][512] bf16
    unsigned short* __restrict__ H1,         // [M][256] bf16 out
    int M)
{
  __shared__ unsigned short As[2][64 * 32];   // 2 x 4 KB
  __shared__ unsigned short Bs[2][256 * 32];  // 2 x 16 KB
  const int tid = threadIdx.x;
  const int wid = tid >> 6, lane = tid & 63;
  const int wc = wid;                      // wave col-quadrant (0..3)
  const int m0 = blockIdx.x * 64;

  // A staging: thread -> row ar (0..63), slot ac (0..3); row clamped so every
  // wave issues exactly 2 loads (vmcnt accounting); garbage rows never stored.
  const int ar = tid >> 2;
  const int ac = tid & 3;
  const int arow = min(m0 + ar, M - 1);
  const int aphys = ac ^ ((ar >> 1) & 3);

  // B staging: wave stages 4 groups of 16 cols; per-lane pre-swizzled source
  const int bq = lane >> 2;                          // col within group
  const int bslotx = (lane & 3) ^ ((lane >> 3) & 3); // source k-slot

  float4 alo, ahi;
  auto loadA = [&](int k0) {
    alo = *(const float4*)&x[(size_t)arow * 512 + k0 + ac * 8];
    ahi = *(const float4*)&x[(size_t)arow * 512 + k0 + ac * 8 + 4];
  };
  auto writeA = [&](int buf) {
    ushort8 o;
    o[0] = f2bf(alo.x); o[1] = f2bf(alo.y); o[2] = f2bf(alo.z); o[3] = f2bf(alo.w);
    o[4] = f2bf(ahi.x); o[5] = f2bf(ahi.y); o[6] = f2bf(ahi.z); o[7] = f2bf(ahi.w);
    *(ushort8*)((char*)As[buf] + ar * 64 + aphys * 16) = o;
  };
  auto stageB = [&](int k0, int buf) {
#pragma unroll
    for (int i = 0; i < 4; ++i) {
      int g = wid + 4 * i;                 // group 0..15 (16 cols each)
      int col = g * 16 + bq;
      gload_lds16(&w1t[(size_t)col * 512 + k0 + bslotx * 8],
                  (char*)Bs[buf] + g * 1024);
    }
  };

  f32x4 acc[4][4] = {};

  // prologue: stage kt=0 into buf 0 (full drain once)
  loadA(0);
  stageB(0, 0);
  writeA(0);
  __syncthreads();

  for (int kt = 0; kt < 16; ++kt) {
    const int cur = kt & 1, nxt = cur ^ 1;
    if (kt < 15) {
      loadA((kt + 1) * 32);        // 2 global loads -> regs (in flight)
      stageB((kt + 1) * 32, nxt);  // 4 global_load_lds (in flight)
      // prev tile's staging (issued last iter, 6 ops older than ours) done:
      asm volatile("s_waitcnt vmcnt(6)" ::: "memory");
    } else {
      asm volatile("s_waitcnt vmcnt(0)" ::: "memory");
    }
    short8 a[4], b[4];
#pragma unroll
    for (int m = 0; m < 4; ++m) {
      int row = m * 16 + (lane & 15);
      int phys = (lane >> 4) ^ ((row >> 1) & 3);
      a[m] = *(const short8*)((const char*)As[cur] + row * 64 + phys * 16);
    }
#pragma unroll
    for (int n = 0; n < 4; ++n) {
      int col = wc * 64 + n * 16 + (lane & 15);
      int phys = (lane >> 4) ^ ((col >> 1) & 3);
      b[n] = *(const short8*)((const char*)Bs[cur] + col * 64 + phys * 16);
    }
#pragma unroll
    for (int m = 0; m < 4; ++m)
#pragma unroll
      for (int n = 0; n < 4; ++n)
        acc[m][n] = __builtin_amdgcn_mfma_f32_16x16x32_bf16(a[m], b[n], acc[m][n], 0, 0, 0);
    if (kt < 15) writeA(nxt);      // compiler waits vmcnt(4) for A regs
    // my ds ops done, then raw barrier (B prefetch stays in flight):
    asm volatile("s_waitcnt lgkmcnt(0)" ::: "memory");
    __builtin_amdgcn_s_barrier();
  }

  const int colbase = wc * 64 + (lane & 15);
#pragma unroll
  for (int m = 0; m < 4; ++m) {
    int rowbase = m0 + m * 16 + (lane >> 4) * 4;
#pragma unroll
    for (int j = 0; j < 4; ++j) {
      int row = rowbase + j;
      if (row < M) {
#pragma unroll
        for (int n = 0; n < 4; ++n)
          H1[(size_t)row * 256 + colbase + n * 16] = f2bf(acc[m][n][j]);
      }
    }
  }
}

// ---------------- GEMM2: H2_bf16[M,64] = relu(bn1(H1AGG_bf16)) @ W2 (MFMA) -------
__global__ __launch_bounds__(256) void gemm2_mfma(
    const unsigned short* __restrict__ A,    // H1AGG bf16 [Mpad][256]
    const unsigned short* __restrict__ w2t,  // [64][256] bf16
    const float* __restrict__ scsh,          // [256] scale | [256] shift
    unsigned short* __restrict__ H2,         // [M][64] bf16 out
    int M)
{
  __shared__ unsigned short As[128 * 64];  // 16 KB
  __shared__ unsigned short Bs[64 * 64];   // 8 KB
  const int tid = threadIdx.x;
  const int wid = tid >> 6, lane = tid & 63;
  const int wr = wid >> 1, wc = wid & 1;
  const int m0 = blockIdx.x * 128;

  const int srow = tid >> 3;
  const int ls = ((tid & 7) ^ (srow & 7)) * 8;
  const unsigned short* gB = &w2t[(size_t)srow * 256 + ls];
  char* lB = (char*)Bs + (size_t)wid * 1024;

  f32x4 acc[4][2] = {};

  for (int kt = 0; kt < 4; ++kt) {
    const int k0 = kt * 64;
#pragma unroll
    for (int i = 0; i < 2; ++i)
      gload_lds16(gB + (size_t)i * 32 * 256 + k0, lB + (size_t)i * 4096);
#pragma unroll
    for (int i = 0; i < 4; ++i) {
      int chunk = tid + 256 * i;
      int r = chunk >> 3, c = chunk & 7;
      int gk = k0 + c * 8;
      ushort8 u = *(const ushort8*)&A[(size_t)(m0 + r) * 256 + gk];
      float4 sc0 = *(const float4*)&scsh[gk];
      float4 sc1 = *(const float4*)&scsh[gk + 4];
      float4 sh0 = *(const float4*)&scsh[256 + gk];
      float4 sh1 = *(const float4*)&scsh[256 + gk + 4];
      ushort8 o;
      o[0] = f2bf(fmaxf(bf2f(u[0]) * sc0.x + sh0.x, 0.f));
      o[1] = f2bf(fmaxf(bf2f(u[1]) * sc0.y + sh0.y, 0.f));
      o[2] = f2bf(fmaxf(bf2f(u[2]) * sc0.z + sh0.z, 0.f));
      o[3] = f2bf(fmaxf(bf2f(u[3]) * sc0.w + sh0.w, 0.f));
      o[4] = f2bf(fmaxf(bf2f(u[4]) * sc1.x + sh1.x, 0.f));
      o[5] = f2bf(fmaxf(bf2f(u[5]) * sc1.y + sh1.y, 0.f));
      o[6] = f2bf(fmaxf(bf2f(u[6]) * sc1.z + sh1.z, 0.f));
      o[7] = f2bf(fmaxf(bf2f(u[7]) * sc1.w + sh1.w, 0.f));
      *(ushort8*)((char*)As + r * 128 + ((c ^ (r & 7)) * 16)) = o;
    }
    __syncthreads();

#pragma unroll
    for (int kk = 0; kk < 2; ++kk) {
      short8 a[4], b[2];
#pragma unroll
      for (int m = 0; m < 4; ++m) {
        int row = wr * 64 + m * 16 + (lane & 15);
        int phys = (kk * 4 + (lane >> 4)) ^ (row & 7);
        a[m] = *(const short8*)((const char*)As + row * 128 + phys * 16);
      }
#pragma unroll
      for (int n = 0; n < 2; ++n) {
        int col = wc * 32 + n * 16 + (lane & 15);
        int phys = (kk * 4 + (lane >> 4)) ^ (col & 7);
        b[n] = *(const short8*)((const char*)Bs + col * 128 + phys * 16);
      }
#pragma unroll
      for (int m = 0; m < 4; ++m)
#pragma unroll
        for (int n = 0; n < 2; ++n)
          acc[m][n] = __builtin_amdgcn_mfma_f32_16x16x32_bf16(a[m], b[n], acc[m][n], 0, 0, 0);
    }
    __syncthreads();
  }

  const int colbase = wc * 32 + (lane & 15);
#pragma unroll
  for (int m = 0; m < 4; ++m) {
    int rowbase = m0 + wr * 64 + m * 16 + (lane >> 4) * 4;
#pragma unroll
    for (int j = 0; j < 4; ++j) {
      int row = rowbase + j;
      if (row < M) {
#pragma unroll
        for (int n = 0; n < 2; ++n)
          H2[(size_t)row * 64 + colbase + n * 16] = f2bf(acc[m][n][j]);
      }
    }
  }
}

// ---------------- CSR build: histogram -> 3-phase scan -> scatter ----------------
__global__ __launch_bounds__(256) void edge_hist(
    const int* __restrict__ rows, int* __restrict__ cnt, int E)
{
  int e = blockIdx.x * 256 + threadIdx.x;
  if (e < E) atomicAdd(&cnt[rows[e]], 1);
}

__global__ __launch_bounds__(256) void scan_blocksum(
    const int* __restrict__ cnt, int* __restrict__ bsum, int Nrows)
{
  int i = blockIdx.x * 256 + threadIdx.x;
  int v = (i < Nrows) ? cnt[i] : 0;
#pragma unroll
  for (int off = 1; off < 64; off <<= 1) v += __shfl_xor(v, off);
  __shared__ int wsum[4];
  if ((threadIdx.x & 63) == 0) wsum[threadIdx.x >> 6] = v;
  __syncthreads();
  if (threadIdx.x == 0)
    bsum[blockIdx.x] = wsum[0] + wsum[1] + wsum[2] + wsum[3];
}

__global__ __launch_bounds__(256) void scan_boff(
    const int* __restrict__ bsum, int* __restrict__ boff, int NB)
{
  __shared__ int lds[256];
  int t = threadIdx.x;
  int v = (t < NB) ? bsum[t] : 0;
  lds[t] = v;
  __syncthreads();
  for (int off = 1; off < 256; off <<= 1) {
    int u = (t >= off) ? lds[t - off] : 0;
    __syncthreads();
    lds[t] += u;
    __syncthreads();
  }
  boff[t] = (t == 0) ? 0 : lds[t - 1];
}

__global__ __launch_bounds__(256) void scan_write(
    const int* __restrict__ cnt, const int* __restrict__ boff,
    int* __restrict__ rowptr, int* __restrict__ cursor, int Nrows, int E)
{
  __shared__ int lds[256];
  int t = threadIdx.x;
  int i = blockIdx.x * 256 + t;
  int v = (i < Nrows) ? cnt[i] : 0;
  lds[t] = v;
  __syncthreads();
  for (int off = 1; off < 256; off <<= 1) {
    int u = (t >= off) ? lds[t - off] : 0;
    __syncthreads();
    lds[t] += u;
    __syncthreads();
  }
  int excl = boff[blockIdx.x] + lds[t] - v;
  if (i < Nrows) { rowptr[i] = excl; cursor[i] = excl; }
  if (i == Nrows) rowptr[i] = E;
}

__global__ __launch_bounds__(256) void edge_scatter(
    const int* __restrict__ rows, const int* __restrict__ cols,
    const float* __restrict__ vals, int* __restrict__ cursor,
    int2* __restrict__ spack, int E)
{
  int e = blockIdx.x * 256 + threadIdx.x;
  if (e < E) {
    int r = rows[e];
    int p = atomicAdd(&cursor[r], 1);
    spack[p] = make_int2(cols[e], __float_as_int(vals[e]));
  }
}

// ---------------- SpMM gather (bf16 D, F=256) -> bf16 out, 8-deep ILP ------------
__global__ __launch_bounds__(256) void spmm_gather_bf(
    const int* __restrict__ rowptr, const int2* __restrict__ sp,
    const unsigned short* __restrict__ D,
    unsigned short* __restrict__ out, int Nrows)
{
  const int lane = threadIdx.x & 63;
  const int r = blockIdx.x * 4 + (threadIdx.x >> 6);
  if (r >= Nrows) return;
  const int s = rowptr[r], e = rowptr[r + 1];
  float4 acc0 = make_float4(0.f, 0.f, 0.f, 0.f);
  float4 acc1 = make_float4(0.f, 0.f, 0.f, 0.f);
  int j = s;
  for (; j + 7 < e; j += 8) {
    int2 p[8];
    ushort4 d[8];
#pragma unroll
    for (int t = 0; t < 8; ++t) p[t] = sp[j + t];
#pragma unroll
    for (int t = 0; t < 8; ++t)
      d[t] = *(const ushort4*)&D[(size_t)p[t].x * 256 + lane * 4];
#pragma unroll
    for (int t = 0; t < 8; t += 2) {
      float v0 = __int_as_float(p[t].y), v1 = __int_as_float(p[t + 1].y);
      acc0.x = fmaf(v0, bf2f(d[t].x), acc0.x); acc0.y = fmaf(v0, bf2f(d[t].y), acc0.y);
      acc0.z = fmaf(v0, bf2f(d[t].z), acc0.z); acc0.w = fmaf(v0, bf2f(d[t].w), acc0.w);
      acc1.x = fmaf(v1, bf2f(d[t + 1].x), acc1.x); acc1.y = fmaf(v1, bf2f(d[t + 1].y), acc1.y);
      acc1.z = fmaf(v1, bf2f(d[t + 1].z), acc1.z); acc1.w = fmaf(v1, bf2f(d[t + 1].w), acc1.w);
    }
  }
  for (; j + 1 < e; j += 2) {
    int2 p0 = sp[j], p1 = sp[j + 1];
    ushort4 d0 = *(const ushort4*)&D[(size_t)p0.x * 256 + lane * 4];
    ushort4 d1 = *(const ushort4*)&D[(size_t)p1.x * 256 + lane * 4];
    float v0 = __int_as_float(p0.y), v1 = __int_as_float(p1.y);
    acc0.x = fmaf(v0, bf2f(d0.x), acc0.x); acc0.y = fmaf(v0, bf2f(d0.y), acc0.y);
    acc0.z = fmaf(v0, bf2f(d0.z), acc0.z); acc0.w = fmaf(v0, bf2f(d0.w), acc0.w);
    acc1.x = fmaf(v1, bf2f(d1.x), acc1.x); acc1.y = fmaf(v1, bf2f(d1.y), acc1.y);
    acc1.z = fmaf(v1, bf2f(d1.z), acc1.z); acc1.w = fmaf(v1, bf2f(d1.w), acc1.w);
  }
  if (j < e) {
    int2 p = sp[j];
    float v = __int_as_float(p.y);
    ushort4 d = *(const ushort4*)&D[(size_t)p.x * 256 + lane * 4];
    acc0.x = fmaf(v, bf2f(d.x), acc0.x); acc0.y = fmaf(v, bf2f(d.y), acc0.y);
    acc0.z = fmaf(v, bf2f(d.z), acc0.z); acc0.w = fmaf(v, bf2f(d.w), acc0.w);
  }
  ushort4 ov;
  ov.x = f2bf(acc0.x + acc1.x); ov.y = f2bf(acc0.y + acc1.y);
  ov.z = f2bf(acc0.z + acc1.z); ov.w = f2bf(acc0.w + acc1.w);
  *(ushort4*)&out[(size_t)r * 256 + lane * 4] = ov;
}

// ---------------- SpMM gather (bf16 D, F=64) -> fp32 out, 8-deep ILP -------------
__global__ __launch_bounds__(256) void spmm_gather_bf64(
    const int* __restrict__ rowptr, const int2* __restrict__ sp,
    const unsigned short* __restrict__ D,
    float* __restrict__ out, int Nrows)
{
  const int lane = threadIdx.x & 63;
  const int r = blockIdx.x * 4 + (threadIdx.x >> 6);
  if (r >= Nrows) return;
  const int s = rowptr[r], e = rowptr[r + 1];
  float acc0 = 0.f, acc1 = 0.f;
  int j = s;
  for (; j + 7 < e; j += 8) {
    int2 p[8];
    float d[8];
#pragma unroll
    for (int t = 0; t < 8; ++t) p[t] = sp[j + t];
#pragma unroll
    for (int t = 0; t < 8; ++t) d[t] = bf2f(D[(size_t)p[t].x * 64 + lane]);
#pragma unroll
    for (int t = 0; t < 8; t += 2) {
      acc0 = fmaf(__int_as_float(p[t].y), d[t], acc0);
      acc1 = fmaf(__int_as_float(p[t + 1].y), d[t + 1], acc1);
    }
  }
  for (; j < e; ++j) {
    int2 p = sp[j];
    acc0 = fmaf(__int_as_float(p.y), bf2f(D[(size_t)p.x * 64 + lane]), acc0);
  }
  out[(size_t)r * 64 + lane] = acc0 + acc1;
}

// ---------------- BN1 stats from bf16 H (C=256), per-block partials --------------
__global__ __launch_bounds__(256) void bn_stats_bf256(
    const unsigned short* __restrict__ H, float* __restrict__ partials, int Nrows)
{
  const int cc = threadIdx.x & 31;    // col chunk (8 cols)
  const int c = cc * 8;
  const int rr = threadIdx.x >> 5;    // 0..7
  float s[8] = {}, q[8] = {};
  for (int r = blockIdx.x * 8 + rr; r < Nrows; r += gridDim.x * 8) {
    ushort8 u = *(const ushort8*)&H[(size_t)r * 256 + c];
#pragma unroll
    for (int j = 0; j < 8; ++j) {
      float f = bf2f(u[j]);
      s[j] += f; q[j] += f * f;
    }
  }
  __shared__ float lds[256][16];
  float* L = lds[threadIdx.x];
#pragma unroll
  for (int j = 0; j < 8; ++j) { L[j] = s[j]; L[8 + j] = q[j]; }
  __syncthreads();
  if (rr == 0) {
#pragma unroll
    for (int r2 = 1; r2 < 8; ++r2) {
      float* Mm = lds[cc + r2 * 32];
#pragma unroll
      for (int j = 0; j < 8; ++j) { s[j] += Mm[j]; q[j] += Mm[8 + j]; }
    }
    float* P = &partials[(size_t)blockIdx.x * 512];
#pragma unroll
    for (int j = 0; j < 8; ++j) { P[c + j] = s[j]; P[256 + c + j] = q[j]; }
  }
}

// ---------------- BN stats fp32 (C=64), per-block partials -----------------------
__global__ __launch_bounds__(256) void bn_stats64(
    const float* __restrict__ H, float* __restrict__ partials, int Nrows)
{
  const int cc = threadIdx.x % 16;
  const int c = cc * 4;
  const int rr = threadIdx.x / 16;   // 0..15
  float4 s = make_float4(0.f, 0.f, 0.f, 0.f);
  float4 q = make_float4(0.f, 0.f, 0.f, 0.f);
  for (int r = blockIdx.x * 16 + rr; r < Nrows; r += gridDim.x * 16) {
    float4 v = *(const float4*)&H[(size_t)r * 64 + c];
    s.x += v.x; s.y += v.y; s.z += v.z; s.w += v.w;
    q.x += v.x * v.x; q.y += v.y * v.y; q.z += v.z * v.z; q.w += v.w * v.w;
  }
  __shared__ float lds[256][8];
  float* L = lds[threadIdx.x];
  L[0] = s.x; L[1] = s.y; L[2] = s.z; L[3] = s.w;
  L[4] = q.x; L[5] = q.y; L[6] = q.z; L[7] = q.w;
  __syncthreads();
  if (rr == 0) {
#pragma unroll
    for (int r2 = 1; r2 < 16; ++r2) {
      float* Mm = lds[cc + r2 * 16];
      s.x += Mm[0]; s.y += Mm[1]; s.z += Mm[2]; s.w += Mm[3];
      q.x += Mm[4]; q.y += Mm[5]; q.z += Mm[6]; q.w += Mm[7];
    }
    float* P = &partials[(size_t)blockIdx.x * 128];
    *(float4*)&P[c] = s;
    *(float4*)&P[64 + c] = q;
  }
}

// ---------------- BN finalize (parallel): one block per channel ------------------
template<int C>
__global__ __launch_bounds__(256) void bn_finalize_par(
    const float* __restrict__ partials,
    const float* __restrict__ gamma, const float* __restrict__ beta,
    float* __restrict__ scsh, int G, float invN)
{
  const int c = blockIdx.x;
  const int t = threadIdx.x;
  float sum = 0.f, sq = 0.f;
  for (int g = t; g < G; g += 256) {
    sum += partials[(size_t)g * 2 * C + c];
    sq  += partials[(size_t)g * 2 * C + C + c];
  }
#pragma unroll
  for (int off = 1; off < 64; off <<= 1) {
    sum += __shfl_xor(sum, off);
    sq  += __shfl_xor(sq, off);
  }
  __shared__ float ws[4][2];
  if ((t & 63) == 0) { ws[t >> 6][0] = sum; ws[t >> 6][1] = sq; }
  __syncthreads();
  if (t == 0) {
    sum = ws[0][0] + ws[1][0] + ws[2][0] + ws[3][0];
    sq  = ws[0][1] + ws[1][1] + ws[2][1] + ws[3][1];
    float mean = sum * invN;
    float var = sq * invN - mean * mean;
    float rstd = rsqrtf(var + 1e-5f);
    float sc = gamma[c] * rstd;
    scsh[c] = sc;
    scsh[C + c] = beta[c] - mean * sc;
  }
}

// ---------------- BN2 apply + log_softmax ----------------------------------------
__global__ __launch_bounds__(256) void bn_lsm(
    const float* __restrict__ H, const float* __restrict__ scsh,
    float* __restrict__ out, int Nrows)
{
  int lane = threadIdx.x & 63;
  int r = blockIdx.x * 4 + (threadIdx.x >> 6);
  if (r >= Nrows) return;
  float y = H[(size_t)r * 64 + lane] * scsh[lane] + scsh[64 + lane];
  float m = y;
#pragma unroll
  for (int off = 32; off >= 1; off >>= 1) m = fmaxf(m, __shfl_xor(m, off));
  float ex = expf(y - m);
  float s = ex;
#pragma unroll
  for (int off = 32; off >= 1; off >>= 1) s += __shfl_xor(s, off);
  out[(size_t)r * 64 + lane] = (y - m) - logf(s);
}

extern "C" void kernel_launch(void* const* d_in, const int* in_sizes, int n_in,
                              void* d_out, int out_size, void* d_ws, size_t ws_size,
                              hipStream_t stream) {
  const float* x      = (const float*)d_in[0];
  const int*   erow   = (const int*)  d_in[1];
  const int*   ecol   = (const int*)  d_in[2];
  const float* eval   = (const float*)d_in[3];
  const float* W1     = (const float*)d_in[4];
  // d_in[5] = b1 : cancels exactly in training-mode BN (shift-invariant)
  const float* gamma1 = (const float*)d_in[6];
  const float* beta1  = (const float*)d_in[7];
  const float* W2     = (const float*)d_in[8];
  // d_in[9] = b2 : cancels in BN2
  const float* gamma2 = (const float*)d_in[10];
  const float* beta2  = (const float*)d_in[11];

  const int N = in_sizes[0] / 512;   // 50000
  const int E = in_sizes[1];         // 800000

  char* ws = (char*)d_ws;
  unsigned short* H1b   = (unsigned short*)(ws + 0);
  float* partials1      = (float*)(ws + 0);
  unsigned short* H2b   = (unsigned short*)(ws + 0);
  float* H2AGG          = (float*)(ws + 12800000);
  unsigned short* H1AGGb= (unsigned short*)(ws + 51200000);
  float* partials2      = (float*)(ws + 51200000);
  unsigned short* w1t   = (unsigned short*)(ws + 76865536);   // 256 KB
  float* scsh1          = (float*)(ws + 77127680);            // 512 f
  float* scsh2          = (float*)(ws + 77129728);            // 128 f
  int*   rowptr         = (int*)(ws + 77130240);
  int*   cnt            = (int*)(ws + 77330244);
  int*   cursor         = (int*)(ws + 77530244);
  int2*  spack          = (int2*)(ws + 77730248);             // E * 8 B (8-aligned)
  int*   bsum           = (int*)(ws + 84130248);
  int*   boff           = (int*)(ws + 84131272);
  unsigned short* w2t   = (unsigned short*)(ws + 84132352);   // 32 KB

  hipMemsetAsync(cnt, 0, (size_t)N * 4, stream);

  const dim3 blk(256);
  const int eblocks = (E + 255) / 256;
  const int NB = (N + 255) / 256;   // 196 <= 256

  // CSR build
  edge_hist<<<eblocks, blk, 0, stream>>>(erow, cnt, E);
  scan_blocksum<<<NB, blk, 0, stream>>>(cnt, bsum, N);
  scan_boff<<<1, blk, 0, stream>>>(bsum, boff, NB);
  scan_write<<<NB + 1, blk, 0, stream>>>(cnt, boff, rowptr, cursor, N, E);
  edge_scatter<<<eblocks, blk, 0, stream>>>(erow, ecol, eval, cursor, spack, E);

  // weight conversions (one kernel)
  cvt_weights<<<576, blk, 0, stream>>>(W1, W2, w1t, w2t);

  // layer 1: H1 = x @ W1 (fp32 in, cast fused, bf16 out) — counted-vmcnt pipeline
  gemm1_mfma<<<(N + 63) / 64, blk, 0, stream>>>(x, w1t, H1b, N);
  // H1AGG = A @ H1 (gather, bf16 out)
  spmm_gather_bf<<<(N + 3) / 4, blk, 0, stream>>>(rowptr, spack, H1b, H1AGGb, N);
  // BN1
  bn_stats_bf256<<<256, blk, 0, stream>>>(H1AGGb, partials1, N);
  bn_finalize_par<256><<<256, blk, 0, stream>>>(partials1, gamma1, beta1, scsh1, 256, 1.0f / N);
  // layer 2: H2 = relu(bn1(H1AGG)) @ W2 (MFMA, BN fused in A-stage, bf16 out)
  gemm2_mfma<<<(N + 127) / 128, blk, 0, stream>>>(H1AGGb, w2t, scsh1, H2b, N);
  // H2AGG = A @ H2 (gather from bf16, fp32 out)
  spmm_gather_bf64<<<(N + 3) / 4, blk, 0, stream>>>(rowptr, spack, H2b, H2AGG, N);
  // BN2
  bn_stats64<<<256, blk, 0, stream>>>(H2AGG, partials2, N);
  bn_finalize_par<64><<<64, blk, 0, stream>>>(partials2, gamma2, beta2, scsh2, 256, 1.0f / N);
  // BN2 apply + log_softmax
  bn_lsm<<<(N + 3) / 4, blk, 0, stream>>>(H2AGG, scsh2, (float*)d_out, N);
}